// Round 1
// baseline (1121.782 us; speedup 1.0000x reference)
//
#include <hip/hip_runtime.h>

// LIIFParametric3DConv — round 13: barrier-free MFMA SIREN MLP.
// R12 was latency-bound (MfmaUtil 12.7%, occupancy 23.5%): the 64 KB LDS
// h1-transpose buffer capped residency at 2 blocks/CU and serialized
// load->mfma->sin->ds_write->barrier->ds_read->mfma per wave.
// This round deletes the LDS round-trip:
//  * layer-1 MFMA operands are SWAPPED (A=W1 frags, B=F frags; identical
//    loads since A/B per-lane maps match) -> each lane ends layer 1 holding
//    h1 of ITS OWN eval row (4 n per quad per n-tile),
//  * layer-2's k index is statically PERMUTED (done once to W2 in prep) so
//    the lane's own packed outputs ARE the layer-2 A-fragment. No shuffles,
//    no LDS, no __syncthreads. h1 lives in 64 VGPRs (u32x4 a2w[2][8]).
// __launch_bounds__(256,3): 0 LDS -> VGPR-bound, target <=168 VGPR,
// 12 waves/CU (was 8).
//
// ws layout (bytes):
//   fhi  @ 0          : 75,497,472  (589824 rows x 64ch bf16, hi)
//   flo  @ 75497472   : 75,497,472  (lo = bf16(f - hi))
//   W1T  @ 150994944  : 32,768      (256 n x 64 k bf16, hi)
//   W1L  @ 151027712  : 32,768      (lo part)
//   W2T  @ 151060480  : 131,072     (256 n x 256 k bf16, k PERMUTED)
//   total 151,191,552

using s16x8 = __attribute__((ext_vector_type(8))) short;
using f32x4 = __attribute__((ext_vector_type(4))) float;
using u32x4 = __attribute__((ext_vector_type(4))) unsigned int;

__device__ __forceinline__ float bf2f(unsigned short u){
  return __uint_as_float(((unsigned)u) << 16);
}
__device__ __forceinline__ short f2bf(float f){
  unsigned b = __float_as_uint(f);
  return (short)((b + 0x7FFFu + ((b >> 16) & 1u)) >> 16);
}
__device__ __forceinline__ unsigned pk2(float lo, float hi){
  return (((unsigned)(unsigned short)f2bf(hi)) << 16)
       |  ((unsigned)(unsigned short)f2bf(lo));
}

// ---------------- prep: W1 -> 256x64 hi/lo bf16, W2 -> 256x256 bf16 ---------
// W2T k-index is permuted so that layer-2 A-fragments are the lanes' own
// layer-1 outputs: k2=(ks<<5)|(q<<3)|j holds W2 row
// R = (2*ks + (j>>2))*16 + q*4 + (j&3)   (bijection on 0..255).
__global__ void prep_kernel(const float* __restrict__ W1, const float* __restrict__ W2,
                            short* __restrict__ W1T, short* __restrict__ W1L,
                            short* __restrict__ W2T){
  const int n = threadIdx.x; // 0..255
  for(int k=0;k<64;k++){
    const float w = W1[(size_t)k*256 + n];
    const short h = f2bf(w);
    W1T[n*64 + k] = h;
    W1L[n*64 + k] = f2bf(w - bf2f((unsigned short)h));
  }
  for(int k2=0;k2<256;k2++){
    const int ks = k2>>5;
    const int q  = (k2>>3)&3;
    const int j  = k2&7;
    const int R  = (2*ks + (j>>2))*16 + q*4 + (j&3);
    W2T[n*256 + k2] = f2bf(W2[(size_t)R*256 + n]);
  }
}

// ---------------- conv3d 2->64, 3x3x3, SAME; writes hi/lo bf16 --------------
__global__ __launch_bounds__(256) void conv_kernel(
    const float* __restrict__ xr, const float* __restrict__ xi,
    const float* __restrict__ enc_w, const float* __restrict__ enc_b,
    short* __restrict__ fhi, short* __restrict__ flo)
{
  __shared__ __align__(16) float wl[64][56];
  __shared__ float bl[64];
  const int tid = threadIdx.x;
  for(int i=tid;i<3456;i+=256) wl[i/54][i%54] = enc_w[i];
  if(tid<128) wl[tid>>1][54+(tid&1)] = 0.f;
  if(tid<64)  bl[tid] = enc_b[tid];
  __syncthreads();

  const unsigned bi   = blockIdx.x;          // 2304 = 2*32*36
  const unsigned tile = bi % 36u;
  const unsigned t    = (bi/36u) % 32u;
  const unsigned b    = bi / 1152u;
  const int h = (int)((tile/6u)*16u) + (tid>>4);
  const int w = (int)((tile%6u)*16u) + (tid&15);

  float xv[56];
  xv[54]=0.f; xv[55]=0.f;
  int k=0;
  #pragma unroll
  for(int i=0;i<2;i++){
    const float* src = i ? xi : xr;
    #pragma unroll
    for(int dz=-1;dz<=1;dz++){
      const int tt = (int)t + dz;
      const bool tok = (tt>=0 && tt<32);
      const size_t tbase = (size_t)(b*32u + (unsigned)(tok?tt:0))*9216u;
      #pragma unroll
      for(int dy=-1;dy<=1;dy++){
        const int hh = h+dy;
        const bool hok = (hh>=0 && hh<96);
        #pragma unroll
        for(int dx=-1;dx<=1;dx++){
          const int ww = w+dx;
          const bool ok = tok && hok && (ww>=0 && ww<96);
          xv[k] = ok ? src[tbase + (size_t)(hh*96+ww)] : 0.f;
          k++;
        }
      }
    }
  }

  const unsigned idx = (b*32u+t)*9216u + (unsigned)(h*96+w);
  short* ph = fhi + (size_t)idx*64u;
  short* pl = flo + (size_t)idx*64u;
  #pragma unroll
  for(int g=0; g<4; g++){
    unsigned hw[8], lw[8];
    #pragma unroll
    for(int c2=0;c2<8;c2++){
      unsigned hpair=0, lpair=0;
      #pragma unroll
      for(int half=0; half<2; half++){
        const int c = g*16 + c2*2 + half;
        float acc = bl[c];
        const float4* wp = (const float4*)(&wl[c][0]);
        #pragma unroll
        for(int qq=0;qq<14;qq++){
          const float4 w4 = wp[qq];
          acc += w4.x*xv[qq*4+0] + w4.y*xv[qq*4+1]
               + w4.z*xv[qq*4+2] + w4.w*xv[qq*4+3];
        }
        const unsigned short hu = (unsigned short)f2bf(acc);
        const unsigned short lu = (unsigned short)f2bf(acc - bf2f(hu));
        hpair |= ((unsigned)hu) << (16*half);
        lpair |= ((unsigned)lu) << (16*half);
      }
      hw[c2]=hpair; lw[c2]=lpair;
    }
    uint4* dh = (uint4*)(ph + g*16);
    uint4* dl = (uint4*)(pl + g*16);
    dh[0] = make_uint4(hw[0],hw[1],hw[2],hw[3]);
    dh[1] = make_uint4(hw[4],hw[5],hw[6],hw[7]);
    dl[0] = make_uint4(lw[0],lw[1],lw[2],lw[3]);
    dl[1] = make_uint4(lw[4],lw[5],lw[6],lw[7]);
  }
}

// ---------------- fused SIREN MLP + lerp, MFMA 16x16x32 bf16 ----------------
// Block: 4 waves x 32 rows (evals). Eval = pixel*2 + {0=floor,1=ceil}.
// No LDS, no barriers: layer-1 swapped-operand MFMA keeps h1 lane-local;
// layer-2 k-permutation (baked into W2T) makes the packed outputs the
// A-fragment directly.
__global__ __launch_bounds__(256, 3) void mlp_kernel(
  const float* __restrict__ tcoord,
  const short* __restrict__ fhi, const short* __restrict__ flo,
  const short* __restrict__ W1T, const short* __restrict__ W1L,
  const float* __restrict__ W1,  const float* __restrict__ b1,
  const short* __restrict__ W2T, const float* __restrict__ b2,
  const float* __restrict__ W3,  const float* __restrict__ b3,
  float* __restrict__ out)
{
  const int tid  = threadIdx.x;
  const int wave = tid>>6;
  const int lane = tid&63;
  const int q  = lane>>4;   // quad
  const int ln = lane&15;
  const unsigned evbase = blockIdx.x*128u + (unsigned)wave*32u;

  // ---- per-lane meta for row (lane&31) ----
  const unsigned rrow = (unsigned)(lane & 31);
  const unsigned ev = evbase + rrow;
  const unsigned pt = ev>>1;
  const unsigned fc = ev&1u;
  const unsigned wq = pt%96u;
  const unsigned hq = (pt/96u)%96u;
  const unsigned jq = (pt/9216u)%32u;
  const unsigned bq = pt/294912u;
  float tc = tcoord[bq*32u+jq];
  tc = fminf(fmaxf(tc, -1.0f), 1.0f - 1e-6f);
  const float dstep = 2.0f/31.0f;
  const int ti = (int)floorf((tc+1.0f)/dstep);
  const unsigned trow = (unsigned)ti + fc;       // <= 31
  const unsigned rowoff = (bq*32u+trow)*9216u + hq*96u + wq;

  const unsigned off0 = __shfl(rowoff, ln, 64);       // row ln
  const unsigned off1 = __shfl(rowoff, 16+ln, 64);    // row 16+ln
  // tc for this lane's OWN eval column (m = rt*16 + ln), used in layer 1
  float tcv[2];
  tcv[0] = __shfl(tc, ln, 64);
  tcv[1] = __shfl(tc, 16+ln, 64);
  // tc per D-row (m = rt*16 + q*4 + rr), used in the lerp epilogue
  float tcm[2][4];
  #pragma unroll
  for(int rt=0;rt<2;rt++)
    #pragma unroll
    for(int rr=0;rr<4;rr++)
      tcm[rt][rr] = __shfl(tc, rt*16 + q*4 + rr, 64);

  // ---- F fragments: per-lane F[m=ln][k=q*8+j], 2 ksteps, hi+lo ----
  s16x8 ahi[2][2], alo[2][2];
  {
    const size_t o0 = (size_t)off0*64u + (size_t)(q*8);
    const size_t o1 = (size_t)off1*64u + (size_t)(q*8);
    ahi[0][0] = *(const s16x8*)(fhi+o0);    ahi[0][1] = *(const s16x8*)(fhi+o0+32);
    ahi[1][0] = *(const s16x8*)(fhi+o1);    ahi[1][1] = *(const s16x8*)(fhi+o1+32);
    alo[0][0] = *(const s16x8*)(flo+o0);    alo[0][1] = *(const s16x8*)(flo+o0+32);
    alo[1][0] = *(const s16x8*)(flo+o1);    alo[1][1] = *(const s16x8*)(flo+o1+32);
  }

  // ---- layer 1 (swapped): D[n-within][m=ln]; lane keeps its own row ----
  // Slot (nt, q, rr) -> h1[n = nt*16+q*4+rr] of eval m = rt*16+ln.
  // Packed into a2w so that a2w[rt][ks] IS the layer-2 A-fragment
  // (k2 = ks*32 + q*8 + j, W2T rows pre-permuted to match).
  u32x4 a2w[2][8];
  #pragma unroll
  for(int nt=0; nt<16; nt++){
    const int nb = nt<<4;
    const short* w1hp = W1T + (nb+ln)*64 + q*8;
    const short* w1lp = W1L + (nb+ln)*64 + q*8;
    const s16x8 bf0 = *(const s16x8*)(w1hp);
    const s16x8 bf1 = *(const s16x8*)(w1hp+32);
    const s16x8 bl0 = *(const s16x8*)(w1lp);
    const s16x8 bl1 = *(const s16x8*)(w1lp+32);
    const float4 b1q = *(const float4*)(b1 + nb + q*4);           // b1[n], n=nb+q*4..+3
    const float4 w1q = *(const float4*)(W1 + 64*256 + nb + q*4);  // W1[64][n] (t-coord col)
    #pragma unroll
    for(int rt=0;rt<2;rt++){
      f32x4 acc = {0.f,0.f,0.f,0.f};
      acc = __builtin_amdgcn_mfma_f32_16x16x32_bf16(bf0, ahi[rt][0], acc, 0,0,0);
      acc = __builtin_amdgcn_mfma_f32_16x16x32_bf16(bf1, ahi[rt][1], acc, 0,0,0);
      acc = __builtin_amdgcn_mfma_f32_16x16x32_bf16(bf0, alo[rt][0], acc, 0,0,0);
      acc = __builtin_amdgcn_mfma_f32_16x16x32_bf16(bf1, alo[rt][1], acc, 0,0,0);
      acc = __builtin_amdgcn_mfma_f32_16x16x32_bf16(bl0, ahi[rt][0], acc, 0,0,0);
      acc = __builtin_amdgcn_mfma_f32_16x16x32_bf16(bl1, ahi[rt][1], acc, 0,0,0);
      const float tcr = tcv[rt];
      const float s0 = __sinf(30.0f*(acc[0] + tcr*w1q.x + b1q.x));
      const float s1 = __sinf(30.0f*(acc[1] + tcr*w1q.y + b1q.y));
      const float s2 = __sinf(30.0f*(acc[2] + tcr*w1q.z + b1q.z));
      const float s3 = __sinf(30.0f*(acc[3] + tcr*w1q.w + b1q.w));
      a2w[rt][nt>>1][(nt&1)*2+0] = pk2(s0,s1);
      a2w[rt][nt>>1][(nt&1)*2+1] = pk2(s2,s3);
    }
  }

  // ---- layer 2 (+3 folded): h2 = sin(30*(h1@W2+b2)); pred = h2@W3 ----
  float pacc[2][4];
  #pragma unroll
  for(int rt=0;rt<2;rt++)
    #pragma unroll
    for(int rr=0;rr<4;rr++) pacc[rt][rr]=0.f;

  #pragma unroll 1
  for(int cg=0; cg<4; cg++){
    f32x4 acc2[2][4];
    const f32x4 zv = {0.f,0.f,0.f,0.f};
    #pragma unroll
    for(int rt=0;rt<2;rt++)
      #pragma unroll
      for(int nt=0;nt<4;nt++) acc2[rt][nt] = zv;

    #pragma unroll
    for(int ks=0; ks<8; ks++){
      const s16x8 a20 = __builtin_bit_cast(s16x8, a2w[0][ks]);
      const s16x8 a21 = __builtin_bit_cast(s16x8, a2w[1][ks]);
      #pragma unroll
      for(int nt=0;nt<4;nt++){
        const int n = cg*64 + nt*16 + ln;
        const s16x8 bfr = *(const s16x8*)(W2T + n*256 + ks*32 + q*8);
        acc2[0][nt] = __builtin_amdgcn_mfma_f32_16x16x32_bf16(a20, bfr, acc2[0][nt], 0,0,0);
        acc2[1][nt] = __builtin_amdgcn_mfma_f32_16x16x32_bf16(a21, bfr, acc2[1][nt], 0,0,0);
      }
    }
    #pragma unroll
    for(int nt=0;nt<4;nt++){
      const int n = cg*64 + nt*16 + ln;
      const float b2v = b2[n];
      const float w3v = W3[n];
      #pragma unroll
      for(int rt=0;rt<2;rt++)
        #pragma unroll
        for(int rr=0;rr<4;rr++){
          const float h2 = __sinf(30.0f*(acc2[rt][nt][rr] + b2v));
          pacc[rt][rr] += h2*w3v;
        }
    }
  }

  // reduce over the 16 n-lanes (xor within ln bits keeps q fixed)
  #pragma unroll
  for(int rt=0;rt<2;rt++)
    #pragma unroll
    for(int rr=0;rr<4;rr++){
      float v = pacc[rt][rr];
      v += __shfl_xor(v, 1, 64);
      v += __shfl_xor(v, 2, 64);
      v += __shfl_xor(v, 4, 64);
      v += __shfl_xor(v, 8, 64);
      pacc[rt][rr] = v;
    }

  // ---- fused lerp: rows (2s, 2s+1) = (floor, ceil) of one pixel ----
  if(ln==0){
    const float b3v = b3[0];
    #pragma unroll
    for(int rt=0;rt<2;rt++){
      #pragma unroll
      for(int s=0;s<2;s++){
        const int m0 = rt*16 + q*4 + 2*s;
        const float tcp = tcm[rt][2*s];
        const int tip = (int)floorf((tcp+1.0f)/dstep);
        const float fci = (float)((double)tip*(2.0/31.0) - 1.0);
        const float tau = (tcp - fci)/dstep;
        const unsigned px = (evbase + (unsigned)m0)>>1;
        out[px] = pacc[rt][2*s]*(1.0f-tau) + pacc[rt][2*s+1]*tau + b3v;
      }
    }
  }
}

extern "C" void kernel_launch(void* const* d_in, const int* in_sizes, int n_in,
                              void* d_out, int out_size, void* d_ws, size_t ws_size,
                              hipStream_t stream){
  const float* xr     = (const float*)d_in[0];
  const float* xi     = (const float*)d_in[1];
  const float* tcoord = (const float*)d_in[2];
  const float* enc_w  = (const float*)d_in[3];
  const float* enc_b  = (const float*)d_in[4];
  const float* W1     = (const float*)d_in[5];
  const float* b1     = (const float*)d_in[6];
  const float* W2     = (const float*)d_in[7];
  const float* b2     = (const float*)d_in[8];
  const float* W3     = (const float*)d_in[9];
  const float* b3     = (const float*)d_in[10];

  char* ws = (char*)d_ws;
  short* fhi  = (short*)(ws);
  short* flo  = (short*)(ws + 75497472);
  short* W1T  = (short*)(ws + 150994944);
  short* W1L  = (short*)(ws + 151027712);
  short* W2T  = (short*)(ws + 151060480);
  float* out  = (float*)d_out;

  hipLaunchKernelGGL(prep_kernel, dim3(1),    dim3(256), 0, stream, W1, W2, W1T, W1L, W2T);
  hipLaunchKernelGGL(conv_kernel, dim3(2304), dim3(256), 0, stream, xr, xi, enc_w, enc_b, fhi, flo);
  hipLaunchKernelGGL(mlp_kernel,  dim3(9216), dim3(256), 0, stream, tcoord, fhi, flo,
                     W1T, W1L, W1, b1, W2T, b2, W3, b3, out);
}

// Round 2
// 615.792 us; speedup vs baseline: 1.8217x; 1.8217x over previous
//
#include <hip/hip_runtime.h>

// LIIFParametric3DConv — round 14: fragment-ordered (coalesced) weight loads.
// R13 deleted LDS/barriers but was flat (896us, MfmaUtil 12.5%) -> bottleneck
// is VMEM *transactions*, not latency hiding: every weight-fragment load was
// a 64-lane gather at 128/512B lane stride = 64 cache lines per instruction,
// ~12.3K transactions/wave ~= 95% of kernel cycles at 1 line/cy/CU.
// This round: prep emits W1/W2 in MFMA-fragment order (fragment f = 1KB,
// lane l owns bytes l*16..+15), so every weight load is base + f*1024 +
// lane*16 — fully coalesced (16 x 64B transactions, 4x fewer). Per-lane
// values are bit-identical to R13 (same (n,k)->lane map, same R(k2) perm).
//
// ws layout (bytes):
//   fhi  @ 0          : 75,497,472  (589824 rows x 64ch bf16, hi)
//   flo  @ 75497472   : 75,497,472  (lo = bf16(f - hi))
//   W1F  @ 150994944  : 32,768      (32 frags x 1KB, fragment-ordered hi)
//   W1FL @ 151027712  : 32,768      (lo part)
//   W2F  @ 151060480  : 131,072     (128 frags x 1KB, fragment-ordered,
//                                    k permuted by R(k2))
//   total 151,191,552

using s16x8 = __attribute__((ext_vector_type(8))) short;
using f32x4 = __attribute__((ext_vector_type(4))) float;
using u32x4 = __attribute__((ext_vector_type(4))) unsigned int;

__device__ __forceinline__ float bf2f(unsigned short u){
  return __uint_as_float(((unsigned)u) << 16);
}
__device__ __forceinline__ short f2bf(float f){
  unsigned b = __float_as_uint(f);
  return (short)((b + 0x7FFFu + ((b >> 16) & 1u)) >> 16);
}
__device__ __forceinline__ unsigned pk2(float lo, float hi){
  return (((unsigned)(unsigned short)f2bf(hi)) << 16)
       |  ((unsigned)(unsigned short)f2bf(lo));
}

// ---------------- prep: fragment-ordered weights -----------------------------
// W1 frag f = nt*2+kk (32 frags): lane l elem j -> n = nt*16+(l&15),
//   k = kk*32+(l>>4)*8+j; value = hi/lo bf16 of W1[k][n].
// W2 frag f = (cg*4+nt)*8+ks (128 frags): lane l elem j ->
//   n = cg*64+nt*16+(l&15), q = l>>4, R = (2*ks+(j>>2))*16+q*4+(j&3);
//   value = bf16(W2[R][n]).  (R is the layer-2 k-permutation: the lane's own
//   packed layer-1 outputs ARE the A-fragment.)
__global__ void prep_kernel(const float* __restrict__ W1, const float* __restrict__ W2,
                            short* __restrict__ W1F, short* __restrict__ W1FL,
                            short* __restrict__ W2F){
  const int tid = threadIdx.x;
  for(int i=tid;i<16384;i+=256){
    const int f = i>>9;
    const int r = i&511;
    const int l = r>>3, j = r&7;
    const int nt = f>>1, kk = f&1;
    const int n = nt*16 + (l&15);
    const int k = kk*32 + (l>>4)*8 + j;
    const float w = W1[(size_t)k*256 + n];
    const short h = f2bf(w);
    W1F[i]  = h;
    W1FL[i] = f2bf(w - bf2f((unsigned short)h));
  }
  for(int i=tid;i<65536;i+=256){
    const int f = i>>9;
    const int r = i&511;
    const int l = r>>3, j = r&7;
    const int ks = f&7;
    const int q  = l>>4;
    const int n  = (f>>5)*64 + ((f>>3)&3)*16 + (l&15);
    const int R  = (2*ks + (j>>2))*16 + q*4 + (j&3);
    W2F[i] = f2bf(W2[(size_t)R*256 + n]);
  }
}

// ---------------- conv3d 2->64, 3x3x3, SAME; writes hi/lo bf16 --------------
__global__ __launch_bounds__(256) void conv_kernel(
    const float* __restrict__ xr, const float* __restrict__ xi,
    const float* __restrict__ enc_w, const float* __restrict__ enc_b,
    short* __restrict__ fhi, short* __restrict__ flo)
{
  __shared__ __align__(16) float wl[64][56];
  __shared__ float bl[64];
  const int tid = threadIdx.x;
  for(int i=tid;i<3456;i+=256) wl[i/54][i%54] = enc_w[i];
  if(tid<128) wl[tid>>1][54+(tid&1)] = 0.f;
  if(tid<64)  bl[tid] = enc_b[tid];
  __syncthreads();

  const unsigned bi   = blockIdx.x;          // 2304 = 2*32*36
  const unsigned tile = bi % 36u;
  const unsigned t    = (bi/36u) % 32u;
  const unsigned b    = bi / 1152u;
  const int h = (int)((tile/6u)*16u) + (tid>>4);
  const int w = (int)((tile%6u)*16u) + (tid&15);

  float xv[56];
  xv[54]=0.f; xv[55]=0.f;
  int k=0;
  #pragma unroll
  for(int i=0;i<2;i++){
    const float* src = i ? xi : xr;
    #pragma unroll
    for(int dz=-1;dz<=1;dz++){
      const int tt = (int)t + dz;
      const bool tok = (tt>=0 && tt<32);
      const size_t tbase = (size_t)(b*32u + (unsigned)(tok?tt:0))*9216u;
      #pragma unroll
      for(int dy=-1;dy<=1;dy++){
        const int hh = h+dy;
        const bool hok = (hh>=0 && hh<96);
        #pragma unroll
        for(int dx=-1;dx<=1;dx++){
          const int ww = w+dx;
          const bool ok = tok && hok && (ww>=0 && ww<96);
          xv[k] = ok ? src[tbase + (size_t)(hh*96+ww)] : 0.f;
          k++;
        }
      }
    }
  }

  const unsigned idx = (b*32u+t)*9216u + (unsigned)(h*96+w);
  short* ph = fhi + (size_t)idx*64u;
  short* pl = flo + (size_t)idx*64u;
  #pragma unroll
  for(int g=0; g<4; g++){
    unsigned hw[8], lw[8];
    #pragma unroll
    for(int c2=0;c2<8;c2++){
      unsigned hpair=0, lpair=0;
      #pragma unroll
      for(int half=0; half<2; half++){
        const int c = g*16 + c2*2 + half;
        float acc = bl[c];
        const float4* wp = (const float4*)(&wl[c][0]);
        #pragma unroll
        for(int qq=0;qq<14;qq++){
          const float4 w4 = wp[qq];
          acc += w4.x*xv[qq*4+0] + w4.y*xv[qq*4+1]
               + w4.z*xv[qq*4+2] + w4.w*xv[qq*4+3];
        }
        const unsigned short hu = (unsigned short)f2bf(acc);
        const unsigned short lu = (unsigned short)f2bf(acc - bf2f(hu));
        hpair |= ((unsigned)hu) << (16*half);
        lpair |= ((unsigned)lu) << (16*half);
      }
      hw[c2]=hpair; lw[c2]=lpair;
    }
    uint4* dh = (uint4*)(ph + g*16);
    uint4* dl = (uint4*)(pl + g*16);
    dh[0] = make_uint4(hw[0],hw[1],hw[2],hw[3]);
    dh[1] = make_uint4(hw[4],hw[5],hw[6],hw[7]);
    dl[0] = make_uint4(lw[0],lw[1],lw[2],lw[3]);
    dl[1] = make_uint4(lw[4],lw[5],lw[6],lw[7]);
  }
}

// ---------------- fused SIREN MLP + lerp, MFMA 16x16x32 bf16 ----------------
// Block: 4 waves x 32 rows (evals). No LDS, no barriers (R13 structure).
// All weight loads are fragment-ordered: base + f*1024 + lane*16 (coalesced).
__global__ __launch_bounds__(256, 3) void mlp_kernel(
  const float* __restrict__ tcoord,
  const short* __restrict__ fhi, const short* __restrict__ flo,
  const short* __restrict__ W1F, const short* __restrict__ W1FL,
  const float* __restrict__ W1,  const float* __restrict__ b1,
  const short* __restrict__ W2F, const float* __restrict__ b2,
  const float* __restrict__ W3,  const float* __restrict__ b3,
  float* __restrict__ out)
{
  const int tid  = threadIdx.x;
  const int wave = tid>>6;
  const int lane = tid&63;
  const int q  = lane>>4;   // quad
  const int ln = lane&15;
  const unsigned evbase = blockIdx.x*128u + (unsigned)wave*32u;

  // ---- per-lane meta for row (lane&31) ----
  const unsigned rrow = (unsigned)(lane & 31);
  const unsigned ev = evbase + rrow;
  const unsigned pt = ev>>1;
  const unsigned fc = ev&1u;
  const unsigned wq = pt%96u;
  const unsigned hq = (pt/96u)%96u;
  const unsigned jq = (pt/9216u)%32u;
  const unsigned bq = pt/294912u;
  float tc = tcoord[bq*32u+jq];
  tc = fminf(fmaxf(tc, -1.0f), 1.0f - 1e-6f);
  const float dstep = 2.0f/31.0f;
  const int ti = (int)floorf((tc+1.0f)/dstep);
  const unsigned trow = (unsigned)ti + fc;       // <= 31
  const unsigned rowoff = (bq*32u+trow)*9216u + hq*96u + wq;

  const unsigned off0 = __shfl(rowoff, ln, 64);       // row ln
  const unsigned off1 = __shfl(rowoff, 16+ln, 64);    // row 16+ln
  // tc for this lane's OWN eval column (m = rt*16 + ln), used in layer 1
  float tcv[2];
  tcv[0] = __shfl(tc, ln, 64);
  tcv[1] = __shfl(tc, 16+ln, 64);
  // tc per D-row (m = rt*16 + q*4 + rr), used in the lerp epilogue
  float tcm[2][4];
  #pragma unroll
  for(int rt=0;rt<2;rt++)
    #pragma unroll
    for(int rr=0;rr<4;rr++)
      tcm[rt][rr] = __shfl(tc, rt*16 + q*4 + rr, 64);

  // ---- F fragments: per-lane F[m=ln][k=q*8+j], 2 ksteps, hi+lo ----
  s16x8 ahi[2][2], alo[2][2];
  {
    const size_t o0 = (size_t)off0*64u + (size_t)(q*8);
    const size_t o1 = (size_t)off1*64u + (size_t)(q*8);
    ahi[0][0] = *(const s16x8*)(fhi+o0);    ahi[0][1] = *(const s16x8*)(fhi+o0+32);
    ahi[1][0] = *(const s16x8*)(fhi+o1);    ahi[1][1] = *(const s16x8*)(fhi+o1+32);
    alo[0][0] = *(const s16x8*)(flo+o0);    alo[0][1] = *(const s16x8*)(flo+o0+32);
    alo[1][0] = *(const s16x8*)(flo+o1);    alo[1][1] = *(const s16x8*)(flo+o1+32);
  }

  // ---- layer 1 (swapped): D[n-within][m=ln]; lane keeps its own row ----
  // Slot (nt, q, rr) -> h1[n = nt*16+q*4+rr] of eval m = rt*16+ln.
  // Packed into a2w so that a2w[rt][ks] IS the layer-2 A-fragment.
  u32x4 a2w[2][8];
  const int l16 = lane*8;
  #pragma unroll
  for(int nt=0; nt<16; nt++){
    const int nb = nt<<4;
    const s16x8 bf0 = *(const s16x8*)(W1F  + (nt*2+0)*512 + l16);
    const s16x8 bf1 = *(const s16x8*)(W1F  + (nt*2+1)*512 + l16);
    const s16x8 bl0 = *(const s16x8*)(W1FL + (nt*2+0)*512 + l16);
    const s16x8 bl1 = *(const s16x8*)(W1FL + (nt*2+1)*512 + l16);
    const float4 b1q = *(const float4*)(b1 + nb + q*4);           // b1[n], n=nb+q*4..+3
    const float4 w1q = *(const float4*)(W1 + 64*256 + nb + q*4);  // W1[64][n] (t-coord col)
    #pragma unroll
    for(int rt=0;rt<2;rt++){
      f32x4 acc = {0.f,0.f,0.f,0.f};
      acc = __builtin_amdgcn_mfma_f32_16x16x32_bf16(bf0, ahi[rt][0], acc, 0,0,0);
      acc = __builtin_amdgcn_mfma_f32_16x16x32_bf16(bf1, ahi[rt][1], acc, 0,0,0);
      acc = __builtin_amdgcn_mfma_f32_16x16x32_bf16(bf0, alo[rt][0], acc, 0,0,0);
      acc = __builtin_amdgcn_mfma_f32_16x16x32_bf16(bf1, alo[rt][1], acc, 0,0,0);
      acc = __builtin_amdgcn_mfma_f32_16x16x32_bf16(bl0, ahi[rt][0], acc, 0,0,0);
      acc = __builtin_amdgcn_mfma_f32_16x16x32_bf16(bl1, ahi[rt][1], acc, 0,0,0);
      const float tcr = tcv[rt];
      const float s0 = __sinf(30.0f*(acc[0] + tcr*w1q.x + b1q.x));
      const float s1 = __sinf(30.0f*(acc[1] + tcr*w1q.y + b1q.y));
      const float s2 = __sinf(30.0f*(acc[2] + tcr*w1q.z + b1q.z));
      const float s3 = __sinf(30.0f*(acc[3] + tcr*w1q.w + b1q.w));
      a2w[rt][nt>>1][(nt&1)*2+0] = pk2(s0,s1);
      a2w[rt][nt>>1][(nt&1)*2+1] = pk2(s2,s3);
    }
  }

  // ---- layer 2 (+3 folded): h2 = sin(30*(h1@W2+b2)); pred = h2@W3 ----
  float pacc[2][4];
  #pragma unroll
  for(int rt=0;rt<2;rt++)
    #pragma unroll
    for(int rr=0;rr<4;rr++) pacc[rt][rr]=0.f;

  #pragma unroll 1
  for(int cg=0; cg<4; cg++){
    f32x4 acc2[2][4];
    const f32x4 zv = {0.f,0.f,0.f,0.f};
    #pragma unroll
    for(int rt=0;rt<2;rt++)
      #pragma unroll
      for(int nt=0;nt<4;nt++) acc2[rt][nt] = zv;

    #pragma unroll
    for(int ks=0; ks<8; ks++){
      const s16x8 a20 = __builtin_bit_cast(s16x8, a2w[0][ks]);
      const s16x8 a21 = __builtin_bit_cast(s16x8, a2w[1][ks]);
      #pragma unroll
      for(int nt=0;nt<4;nt++){
        const s16x8 bfr = *(const s16x8*)(W2F + (((cg*4+nt)*8+ks)*512) + l16);
        acc2[0][nt] = __builtin_amdgcn_mfma_f32_16x16x32_bf16(a20, bfr, acc2[0][nt], 0,0,0);
        acc2[1][nt] = __builtin_amdgcn_mfma_f32_16x16x32_bf16(a21, bfr, acc2[1][nt], 0,0,0);
      }
    }
    #pragma unroll
    for(int nt=0;nt<4;nt++){
      const int n = cg*64 + nt*16 + ln;
      const float b2v = b2[n];
      const float w3v = W3[n];
      #pragma unroll
      for(int rt=0;rt<2;rt++)
        #pragma unroll
        for(int rr=0;rr<4;rr++){
          const float h2 = __sinf(30.0f*(acc2[rt][nt][rr] + b2v));
          pacc[rt][rr] += h2*w3v;
        }
    }
  }

  // reduce over the 16 n-lanes (xor within ln bits keeps q fixed)
  #pragma unroll
  for(int rt=0;rt<2;rt++)
    #pragma unroll
    for(int rr=0;rr<4;rr++){
      float v = pacc[rt][rr];
      v += __shfl_xor(v, 1, 64);
      v += __shfl_xor(v, 2, 64);
      v += __shfl_xor(v, 4, 64);
      v += __shfl_xor(v, 8, 64);
      pacc[rt][rr] = v;
    }

  // ---- fused lerp: rows (2s, 2s+1) = (floor, ceil) of one pixel ----
  if(ln==0){
    const float b3v = b3[0];
    #pragma unroll
    for(int rt=0;rt<2;rt++){
      #pragma unroll
      for(int s=0;s<2;s++){
        const int m0 = rt*16 + q*4 + 2*s;
        const float tcp = tcm[rt][2*s];
        const int tip = (int)floorf((tcp+1.0f)/dstep);
        const float fci = (float)((double)tip*(2.0/31.0) - 1.0);
        const float tau = (tcp - fci)/dstep;
        const unsigned px = (evbase + (unsigned)m0)>>1;
        out[px] = pacc[rt][2*s]*(1.0f-tau) + pacc[rt][2*s+1]*tau + b3v;
      }
    }
  }
}

extern "C" void kernel_launch(void* const* d_in, const int* in_sizes, int n_in,
                              void* d_out, int out_size, void* d_ws, size_t ws_size,
                              hipStream_t stream){
  const float* xr     = (const float*)d_in[0];
  const float* xi     = (const float*)d_in[1];
  const float* tcoord = (const float*)d_in[2];
  const float* enc_w  = (const float*)d_in[3];
  const float* enc_b  = (const float*)d_in[4];
  const float* W1     = (const float*)d_in[5];
  const float* b1     = (const float*)d_in[6];
  const float* W2     = (const float*)d_in[7];
  const float* b2     = (const float*)d_in[8];
  const float* W3     = (const float*)d_in[9];
  const float* b3     = (const float*)d_in[10];

  char* ws = (char*)d_ws;
  short* fhi  = (short*)(ws);
  short* flo  = (short*)(ws + 75497472);
  short* W1F  = (short*)(ws + 150994944);
  short* W1FL = (short*)(ws + 151027712);
  short* W2F  = (short*)(ws + 151060480);
  float* out  = (float*)d_out;

  hipLaunchKernelGGL(prep_kernel, dim3(1),    dim3(256), 0, stream, W1, W2, W1F, W1FL, W2F);
  hipLaunchKernelGGL(conv_kernel, dim3(2304), dim3(256), 0, stream, xr, xi, enc_w, enc_b, fhi, flo);
  hipLaunchKernelGGL(mlp_kernel,  dim3(9216), dim3(256), 0, stream, tcoord, fhi, flo,
                     W1F, W1FL, W1, b1, W2F, b2, W3, b3, out);
}